// Round 11
// baseline (183.687 us; speedup 1.0000x reference)
//
#include <hip/hip_runtime.h>
#include <hip/hip_bf16.h>

typedef __attribute__((ext_vector_type(8))) short bf16x8;    // 8 bf16 = 4 VGPR
typedef __attribute__((ext_vector_type(16))) float f32x16;   // 32x32 accumulator
typedef unsigned int u32;

#define MOD_SCALE 0.04419417382415922f     // 1/sqrt(512)
#define CONV_SCALE 0.014731391274719742f   // 1/sqrt(512*9)

__device__ __forceinline__ unsigned short f2bf(float f) {
  union { float f; u32 u; } v; v.f = f;
  u32 r = v.u + 0x7fffu + ((v.u >> 16) & 1u);   // RNE
  return (unsigned short)(r >> 16);
}

__device__ __forceinline__ void gload_lds16(const void* g, void* l) {
  __builtin_amdgcn_global_load_lds(
      (const __attribute__((address_space(1))) u32*)g,
      (__attribute__((address_space(3))) u32*)l, 16, 0, 0);
}

// 16B-chunk bank swizzle within a 1KB/2KB region: XOR bank-run bits with px[4:2].
// p = c ^ ((c>>3)&7); involution (bits >=3 unchanged). Spreads the 8 lanes that
// share a 4-bank run (fixed px&3,lh) across all 8 run starts.
__device__ __forceinline__ int swz(int c) { return c ^ ((c >> 3) & 7); }

// ---- k_prep: blocks 0..1023 = weight prep (LDS-coalesced), 1024..1039 = style GEMV.
// wb layout: [tap 9][icb 32][oc 512][ic 16] bf16.
__global__ void k_prep(const float* __restrict__ wsrc, ushort* __restrict__ wb,
                       float* __restrict__ wsq, float* __restrict__ zerobuf,
                       const float* __restrict__ style, const float* __restrict__ mw,
                       const float* __restrict__ mb, float* __restrict__ s) {
  __shared__ float wtile[2304];
  const int t = threadIdx.x;
  if (blockIdx.x < 1024) {
    const float4* s4 = (const float4*)(wsrc + (size_t)blockIdx.x * 2304);
    float4* w4 = (float4*)wtile;
    w4[t] = s4[t];
    w4[t + 256] = s4[t + 256];
    if (t < 64) w4[t + 512] = s4[t + 512];
    __syncthreads();
    int idx = blockIdx.x * 256 + t;   // oc*512+ic
    int oc = idx >> 9, ic = idx & 511;
    int icb = ic >> 4, icr = ic & 15;
    if (blockIdx.x == 0 && t < 16) zerobuf[t] = 0.f;
    float sq = 0.f;
    #pragma unroll
    for (int tap = 0; tap < 9; ++tap) {
      float v = wtile[t * 9 + tap];
      sq += v * v;
      wb[((tap * 32 + icb) * 512 + oc) * 16 + icr] = f2bf(v);
    }
    wsq[idx] = sq;
  } else {
    int idx = (blockIdx.x - 1024) * 256 + t;   // b*512+ic
    int b = idx >> 9, ic = idx & 511;
    const float4* wr = (const float4*)(mw + ic * 512);
    const float4* sr = (const float4*)(style + b * 512);
    float acc = 0.f;
    #pragma unroll 4
    for (int k = 0; k < 128; ++k) {
      float4 a = wr[k], c = sr[k];
      acc += a.x * c.x + a.y * c.y + a.z * c.z + a.w * c.w;
    }
    s[idx] = acc * MOD_SCALE + mb[ic];
  }
}

// ---- k_pre2: [0,512) xform -> xsb; [512,528) demod -> dscale (uses wsq + s).
__global__ void k_pre2(const float* __restrict__ x, const float* __restrict__ s,
                       ushort* __restrict__ xsb, const float* __restrict__ wsq,
                       float* __restrict__ dscale) {
  const int t = threadIdx.x;
  if (blockIdx.x < 512) {
    // xform: xsb[b][y][icb 32][x 64][ic 16] = bf16(x[b][ic][y][x] * s[b][ic])
    const int y = blockIdx.x & 63, b = blockIdx.x >> 6;
    const int px = t & 63, icq = t >> 6;
    #pragma unroll
    for (int i = 0; i < 8; ++i) {
      int icb = i * 4 + icq;
      union { ushort u[16]; uint4 v[2]; } pk;
      #pragma unroll
      for (int j = 0; j < 16; ++j) {
        int ic = icb * 16 + j;
        float v = x[(b * 512 + ic) * 4096 + y * 64 + px] * s[b * 512 + ic];
        pk.u[j] = f2bf(v);
      }
      ushort* dst = xsb + ((size_t)((b * 64 + y) * 32 + icb) * 64 + px) * 16;
      *(uint4*)dst = pk.v[0];
      *(uint4*)(dst + 8) = pk.v[1];
    }
  } else {
    // demod: dscale[b][oc] = CONV_SCALE * rsqrt(CONV_SCALE^2 * sum_ic wsq*s^2 + eps)
    int idx = (blockIdx.x - 512) * 256 + t;   // 4096 = b*512+oc
    int b = idx >> 9, oc = idx & 511;
    const float4* wq = (const float4*)(wsq + oc * 512);
    const float4* sp = (const float4*)(s + b * 512);
    float acc = 0.f;
    #pragma unroll 4
    for (int k = 0; k < 128; ++k) {
      float4 a = wq[k], c = sp[k];
      acc += a.x * c.x * c.x + a.y * c.y * c.y + a.z * c.z * c.z + a.w * c.w * c.w;
    }
    dscale[idx] = CONV_SCALE * rsqrtf(CONV_SCALE * CONV_SCALE * acc + 1e-8f);
  }
}

// ---- k_conv: implicit-GEMM conv, mfma_f32_32x32x16_bf16, counted-vmcnt pipeline.
// 512 thr = 8 waves, 1 block/CU; tile 64oc x 16rows x 64px; wave = 4r x 32px x 64oc.
// A double-buffered (2x18432B), B TRIPLE-buffered (3x18 rows x 2080B: 2048 staged
// + 32B zero-line for the x-halo). Per step: issue A(t+1), B(t+2); compute(t);
// s_waitcnt vmcnt(4) (A(t+1)+B(t+1) drained, B(t+2) stays in flight) + s_barrier.
// Fragment reads bank-swizzled at 16B granularity (pre-swizzled global source).
#define BROW   2080
#define ABUF   18432
#define BBUF   (18 * BROW)          // 37440
#define B0OFF  (2 * ABUF)           // 36864
#define DSSOFF (B0OFF + 3 * BBUF)   // 149184
#define SMEMSZ (DSSOFF + 256)       // 149440

__global__ __launch_bounds__(512, 2) void k_conv(
    const ushort* __restrict__ wb, const ushort* __restrict__ xsb,
    const float* __restrict__ dscale, const float* __restrict__ zerobuf,
    float* __restrict__ out) {
  const int yb = blockIdx.x, ocb = blockIdx.y, b = blockIdx.z;
  const int t = threadIdx.x;
  const int wv = t >> 6, l = t & 63;
  const int lc = l & 31, lh = l >> 5;
  const int wvr = wv >> 1, wvp = wv & 1;
  const int y0 = yb * 16, oc0 = ocb * 64;

  extern __shared__ char smem[];
  float* dss = (float*)(smem + DSSOFF);

  f32x16 acc[4][2];
  #pragma unroll
  for (int rr = 0; rr < 4; ++rr)
    #pragma unroll
    for (int ocf = 0; ocf < 2; ++ocf)
      #pragma unroll
      for (int k = 0; k < 16; ++k)
        acc[rr][ocf][k] = 0.f;

  // ---- A staging: 1152 chunks; wave w, instr i covers group g=w+i*8 (g<18).
  // physical chunk pc (linear LDS) holds logical c = swz(pc) -> pre-swizzled source.
  const char* asrc[3];
  #pragma unroll
  for (int i = 0; i < 3; ++i) {
    int cid = (wv + i * 8) * 64 + l;
    int tap = cid >> 7, pc = cid & 127;
    int c64 = swz(pc & 63);
    int oc_l = ((pc >> 6) << 5) + (c64 >> 1), h = c64 & 1;
    if (tap > 8) tap = 8;   // invalid lanes (never issued) — keep ptr sane
    asrc[i] = (const char*)wb + (size_t)tap * 524288 + (size_t)(oc0 + oc_l) * 32 + h * 16;
  }
  // ---- B staging: 2304 chunks = 18 rows x 128; group g=w+i*8 (g<36).
  const char* bsrc[5];
  int bstr[5];
  #pragma unroll
  for (int i = 0; i < 5; ++i) {
    int cid = (wv + i * 8) * 64 + l;
    int r = cid >> 7, pc = cid & 127;
    int c = swz(pc);
    int col = c >> 1, h = c & 1;
    int yy = y0 - 1 + (r < 18 ? r : 17);
    bool inr = ((unsigned)yy < 64u) && (r < 18);
    bsrc[i] = inr ? (const char*)xsb + (size_t)(b * 64 + yy) * 65536 + col * 32 + h * 16
                  : (const char*)zerobuf;
    bstr[i] = inr ? 2048 : 0;
  }

  // fragment-read swizzled offsets
  const int apo = swz(lc * 2 + lh) * 16;
  int boff[3];
  #pragma unroll
  for (int dx = 0; dx < 3; ++dx) {
    int px = wvp * 32 + lc + dx - 1;
    boff[dx] = ((unsigned)px < 64u) ? swz(px * 2 + lh) * 16 : 2048 + lh * 16;
  }

  auto STAGE_A = [&](int kA) {
    char* base = smem + (kA & 1) * ABUF + wv * 1024;
    const int ko = (kA & 31) * 16384;
    #pragma unroll
    for (int i = 0; i < 3; ++i)
      if (i < 2 || wv < 2)
        gload_lds16(asrc[i] + ko, base + i * 8192);
  };
  auto STAGE_B = [&](int kB, char* bbuf) {
    const int ko = (kB & 31);
    #pragma unroll
    for (int i = 0; i < 5; ++i)
      if (i < 4 || wv < 4) {
        int g = wv + i * 8;
        gload_lds16(bsrc[i] + ko * bstr[i], bbuf + (g >> 1) * BROW + (g & 1) * 1024);
      }
  };

  auto COMPUTE = [&](const char* Ab, const char* Bb) {
    #pragma unroll
    for (int dx = 0; dx < 3; ++dx) {
      bf16x8 bfr[6];
      #pragma unroll
      for (int j = 0; j < 6; ++j)
        bfr[j] = *(const bf16x8*)(Bb + (wvr * 4 + j) * BROW + boff[dx]);
      bf16x8 af[3][2];
      #pragma unroll
      for (int dy = 0; dy < 3; ++dy)
        #pragma unroll
        for (int ocf = 0; ocf < 2; ++ocf)
          af[dy][ocf] = *(const bf16x8*)(Ab + (dy * 3 + dx) * 2048 + ocf * 1024 + apo);
      __builtin_amdgcn_s_setprio(1);
      #pragma unroll
      for (int dy = 0; dy < 3; ++dy)
        #pragma unroll
        for (int rr = 0; rr < 4; ++rr)
          #pragma unroll
          for (int ocf = 0; ocf < 2; ++ocf)
            acc[rr][ocf] = __builtin_amdgcn_mfma_f32_32x32x16_bf16(
                af[dy][ocf], bfr[rr + dy], acc[rr][ocf], 0, 0, 0);
      __builtin_amdgcn_s_setprio(0);
    }
  };

  // ---- prologue: dss + zero-lines; stage A(0), B(0), B(1); counted wait.
  if (t < 64) dss[t] = dscale[b * 512 + oc0 + t];
  if (t < 108) {   // 3 bufs x 18 rows x 32B zero-line at row offset 2048
    int line = t >> 1, q = t & 1;
    int bi = line / 18, r = line - bi * 18;
    *(uint4*)(smem + B0OFF + bi * BBUF + r * BROW + 2048 + q * 16) = uint4{0, 0, 0, 0};
  }
  STAGE_A(0);
  STAGE_B(0, smem + B0OFF);
  STAGE_B(1, smem + B0OFF + BBUF);
  asm volatile("s_waitcnt lgkmcnt(0)" ::: "memory");   // dss + zero-lines visible
  asm volatile("s_waitcnt vmcnt(4)");                  // A(0),B(0) landed
  __builtin_amdgcn_s_barrier();
  __builtin_amdgcn_sched_barrier(0);

  char* bc  = smem + B0OFF;
  char* bn1 = smem + B0OFF + BBUF;
  char* bn2 = smem + B0OFF + 2 * BBUF;
  #pragma unroll 1
  for (int it = 0; it < 32; ++it) {
    STAGE_A(it + 1);          // into A buf (it+1)&1  (dead re-read at it=31)
    STAGE_B(it + 2, bn2);     // two steps ahead (dead re-read for it>=30)
    COMPUTE(smem + (it & 1) * ABUF, bc);
    asm volatile("s_waitcnt vmcnt(4)");   // A(t+1)+B(t+1) done; B(t+2) in flight
    __builtin_amdgcn_s_barrier();
    __builtin_amdgcn_sched_barrier(0);
    char* tmp = bc; bc = bn1; bn1 = bn2; bn2 = tmp;
  }

  // ---- epilogue: 32x32 D layout [m74/m101]: col(px)=lane&31, row(oc)=(reg&3)+8*(reg>>2)+4*(lane>>5)
  #pragma unroll
  for (int rr = 0; rr < 4; ++rr) {
    const int y_row = y0 + wvr * 4 + rr;
    #pragma unroll
    for (int ocf = 0; ocf < 2; ++ocf) {
      #pragma unroll
      for (int reg = 0; reg < 16; ++reg) {
        int oc_l = ocf * 32 + (reg & 3) + 8 * (reg >> 2) + 4 * lh;
        out[(size_t)(b * 512 + oc0 + oc_l) * 4096 + y_row * 64 + wvp * 32 + lc]
            = acc[rr][ocf][reg] * dss[oc_l];
      }
    }
  }
}

extern "C" void kernel_launch(void* const* d_in, const int* in_sizes, int n_in,
                              void* d_out, int out_size, void* d_ws, size_t ws_size,
                              hipStream_t stream) {
  const float* x     = (const float*)d_in[0];  // [8,512,64,64]
  const float* style = (const float*)d_in[1];  // [8,512]
  const float* mw    = (const float*)d_in[2];  // [512,512]
  const float* mb    = (const float*)d_in[3];  // [512]
  const float* wsrc  = (const float*)d_in[4];  // [1,512,512,3,3]
  float* out = (float*)d_out;

  char* ws = (char*)d_ws;
  float*  zerobuf = (float*)(ws + 0);          //    64 B
  float*  s       = (float*)(ws + 256);        //  16 KB
  float*  dscale  = (float*)(ws + 16640);      //  16 KB
  float*  wsq     = (float*)(ws + 33024);      //   1 MB
  ushort* wb      = (ushort*)(ws + 1081600);   // 4.5 MB  [9][32][512][16] bf16
  ushort* xsb     = (ushort*)(ws + 5800192);   //  32 MB  [8][64][32][64][16] bf16

  hipFuncSetAttribute(reinterpret_cast<const void*>(k_conv),
                      hipFuncAttributeMaxDynamicSharedMemorySize, SMEMSZ);

  k_prep<<<dim3(1040), dim3(256), 0, stream>>>(wsrc, wb, wsq, zerobuf, style, mw, mb, s);
  k_pre2<<<dim3(528), dim3(256), 0, stream>>>(x, s, xsb, wsq, dscale);
  k_conv<<<dim3(4, 8, 8), dim3(512), SMEMSZ, stream>>>(wb, xsb, dscale, zerobuf, out);
}